// Round 14
// baseline (276.355 us; speedup 1.0000x reference)
//
#include <hip/hip_runtime.h>
#include <hip/hip_bf16.h>

typedef __attribute__((ext_vector_type(8))) __bf16 bf16x8;
typedef __attribute__((ext_vector_type(4))) __bf16 bf16x4;
typedef __attribute__((ext_vector_type(4))) float f32x4;
typedef __attribute__((ext_vector_type(2))) unsigned u32x2;
typedef __attribute__((ext_vector_type(4))) unsigned u32x4;

#define LOG2E 1.4426950408889634f
#define FIXED_M 16.0f

static __device__ __forceinline__ f32x4 mfma16(bf16x8 a, bf16x8 b, f32x4 c) {
  return __builtin_amdgcn_mfma_f32_16x16x32_bf16(a, b, c, 0, 0, 0);
}

static __device__ __forceinline__ void gload_lds16(const void* g, void* l) {
  __builtin_amdgcn_global_load_lds(
      (const __attribute__((address_space(1))) unsigned int*)g,
      (__attribute__((address_space(3))) unsigned int*)l, 16, 0, 0);
}

// ---------------- f32 -> bf16 convert (vectorized) ----------------
__global__ __launch_bounds__(256) void k_cvt(const float* __restrict__ in,
                                             __bf16* __restrict__ out, int n4) {
  for (int i = blockIdx.x * blockDim.x + threadIdx.x; i < n4;
       i += gridDim.x * blockDim.x) {
    float4 v = reinterpret_cast<const float4*>(in)[i];
    bf16x4 o = {(__bf16)v.x, (__bf16)v.y, (__bf16)v.z, (__bf16)v.w};
    reinterpret_cast<bf16x4*>(out)[i] = o;
  }
}

// ---------------- weight convert + transpose: Wt[n][k] = W[k][n] ----------------
__global__ __launch_bounds__(256) void k_wt(const float* __restrict__ W,
                                            __bf16* __restrict__ Wt) {
  __shared__ float tile[64][65];
  int bx = blockIdx.x;
  int by = blockIdx.y;
  int tid = threadIdx.x;
#pragma unroll
  for (int p = 0; p < 16; p++) {
    int idx = p * 256 + tid;
    int r = idx >> 6, c = idx & 63;
    tile[r][c] = W[(size_t)(by * 64 + r) * 512 + bx * 64 + c];
  }
  __syncthreads();
#pragma unroll
  for (int p = 0; p < 16; p++) {
    int idx = p * 256 + tid;
    int rn = idx >> 6, ck = idx & 63;
    Wt[(size_t)(bx * 64 + rn) * 512 + by * 64 + ck] = (__bf16)tile[ck][rn];
  }
}

// ---------------- GEMM: C[M,512] = A[M,512](bf16) @ W (via Wt[n][k] bf16) ----------------
template <int OUT_MODE>
__global__ __launch_bounds__(256) void k_gemm(const __bf16* __restrict__ A,
                                              const __bf16* __restrict__ Bt,
                                              void* __restrict__ Cout,
                                              float scale) {
  constexpr bool SWAP = (OUT_MODE != 2);
  __shared__ __bf16 As[128][72];
  __shared__ __bf16 Bs[64][72];
  const int tid = threadIdx.x;
  const int wid = tid >> 6, lane = tid & 63;
  const int g = lane >> 4, c = lane & 15;
  const int m0 = blockIdx.x * 128, n0 = blockIdx.y * 64;
  const int wr = wid >> 1, wc = wid & 1;

  f32x4 acc[4][2];
#pragma unroll
  for (int i = 0; i < 4; i++)
#pragma unroll
    for (int j = 0; j < 2; j++) acc[i][j] = (f32x4){0.f, 0.f, 0.f, 0.f};

  for (int k0 = 0; k0 < 512; k0 += 64) {
#pragma unroll
    for (int q = 0; q < 4; q++) {
      int idx = (q * 256 + tid) * 8;
      int r = idx >> 6, cc = idx & 63;
      bf16x8 v = *reinterpret_cast<const bf16x8*>(A + (size_t)(m0 + r) * 512 + k0 + cc);
      *reinterpret_cast<bf16x8*>(&As[r][cc]) = v;
    }
#pragma unroll
    for (int q = 0; q < 2; q++) {
      int idx = (q * 256 + tid) * 8;
      int r = idx >> 6, cc = idx & 63;
      bf16x8 v = *reinterpret_cast<const bf16x8*>(Bt + (size_t)(n0 + r) * 512 + k0 + cc);
      *reinterpret_cast<bf16x8*>(&Bs[r][cc]) = v;
    }
    __syncthreads();
#pragma unroll
    for (int kk = 0; kk < 2; kk++) {
      bf16x8 bfrag[2];
#pragma unroll
      for (int nf = 0; nf < 2; nf++)
        bfrag[nf] = *reinterpret_cast<const bf16x8*>(&Bs[wc * 32 + nf * 16 + c][kk * 32 + g * 8]);
#pragma unroll
      for (int mf = 0; mf < 4; mf++) {
        bf16x8 afrag = *reinterpret_cast<const bf16x8*>(&As[wr * 64 + mf * 16 + c][kk * 32 + g * 8]);
#pragma unroll
        for (int nf = 0; nf < 2; nf++)
          acc[mf][nf] = SWAP ? mfma16(bfrag[nf], afrag, acc[mf][nf])
                             : mfma16(afrag, bfrag[nf], acc[mf][nf]);
      }
    }
    __syncthreads();
  }
#pragma unroll
  for (int mf = 0; mf < 4; mf++)
#pragma unroll
    for (int nf = 0; nf < 2; nf++) {
      if (OUT_MODE == 0) {
        int mm = m0 + wr * 64 + mf * 16 + c;
        int nnb = n0 + wc * 32 + nf * 16 + g * 4;
        int b = mm >> 12, s = mm & 4095, h = nnb >> 6, d = nnb & 63;
        bf16x4 ov = {(__bf16)(acc[mf][nf][0] * scale), (__bf16)(acc[mf][nf][1] * scale),
                     (__bf16)(acc[mf][nf][2] * scale), (__bf16)(acc[mf][nf][3] * scale)};
        *reinterpret_cast<bf16x4*>((__bf16*)Cout + ((((size_t)b * 8 + h) * 4096) + s) * 64 + d) = ov;
      } else if (OUT_MODE == 1) {
        int mm = m0 + wr * 64 + mf * 16 + c;
        int nnb = n0 + wc * 32 + nf * 16 + g * 4;
        f32x4 ov = acc[mf][nf] * scale;
        *reinterpret_cast<f32x4*>((float*)Cout + (size_t)mm * 512 + nnb) = ov;
      } else {
        int mmb = m0 + wr * 64 + mf * 16 + g * 4;
        int nn = n0 + wc * 32 + nf * 16 + c;
        int b = mmb >> 12, s = mmb & 4095, h = nn >> 6, d = nn & 63;
        bf16x4 ov = {(__bf16)(acc[mf][nf][0] * scale), (__bf16)(acc[mf][nf][1] * scale),
                     (__bf16)(acc[mf][nf][2] * scale), (__bf16)(acc[mf][nf][3] * scale)};
        *reinterpret_cast<bf16x4*>((__bf16*)Cout + (((size_t)b * 8 + h) * 64 + d) * 4096 + s) = ov;
      }
    }
}

// ---------------- flash attention: batch-paired, fixed-max softmax, P in registers,
// CROSS-CHUNK DEFERRED PV: PV(t-1) (register-only MFMAs) executes inside process(t),
// overlapping QK(t)'s LDS reads / MFMA chain. Tail flush after the loop. ----------------
// 512 blocks, id = (q_hi<<6)|(h<<3)|qb_lo (8 h-blocks of a qb-group per XCD -> L2 bias).
// Block: 64 q-rows x {b=0,b=1}. 4 waves x 16 q. Chunk = 64 keys, both batches staged.
__global__ __launch_bounds__(256, 2) void k_attn(const __bf16* __restrict__ Q,
                                                 const __bf16* __restrict__ K,
                                                 const __bf16* __restrict__ Vt,
                                                 const float* __restrict__ bias,
                                                 __bf16* __restrict__ Out) {
  __shared__ __bf16 KVs[2][2][2][64][64];  // [dbuf][batch][K/V][row][64], XOR-swz (^(row&7)<<4)

  const int id = blockIdx.x;
  const int qb = ((id >> 6) << 3) | (id & 7);  // 0..63
  const int h = (id >> 3) & 7;
  const int tid = threadIdx.x, wid = tid >> 6, lane = tid & 63;
  const int g = lane >> 4, c = lane & 15;
  const int swz = (c & 7) << 4;
  const char* KbP[2] = {(const char*)(K + (size_t)h * 4096 * 64),
                        (const char*)(K + (size_t)(8 + h) * 4096 * 64)};
  const char* VbP[2] = {(const char*)(Vt + (size_t)h * 64 * 4096),
                        (const char*)(Vt + (size_t)(8 + h) * 64 * 4096)};
  const int q0 = qb * 64 + wid * 16;
  const int myq = q0 + c;

  auto stage = [&](int db, int chunk) {
    const int bt = wid >> 1, reg = wid & 1;
    char* dst0 = (char*)&KVs[db][bt][reg][0][0];
#pragma unroll
    for (int j = 0; j < 8; j++) {
      int Lp = j * 1024 + lane * 16;
      int L = Lp ^ (((Lp >> 7) & 7) << 4);
      const char* src = (reg == 0)
          ? KbP[bt] + (size_t)chunk * 8192 + L
          : VbP[bt] + (size_t)(L >> 7) * 8192 + (size_t)chunk * 128 + (L & 127);
      gload_lds16(src, dst0 + j * 1024);
    }
  };

  const float* brow = bias + (size_t)myq * 4096;

#define LOADB(dst, chunk)                                                      \
  {                                                                            \
    _Pragma("unroll") for (int f = 0; f < 4; f++) dst[f] =                     \
        *reinterpret_cast<const f32x4*>(brow + (chunk) * 64 + f * 16 + g * 4); \
  }

  bf16x8 qa[2][2];
  {
    const __bf16* Qh0 = Q + (size_t)h * 4096 * 64;
    const __bf16* Qh1 = Q + (size_t)(8 + h) * 4096 * 64;
    qa[0][0] = *reinterpret_cast<const bf16x8*>(Qh0 + (size_t)myq * 64 + g * 8);
    qa[0][1] = *reinterpret_cast<const bf16x8*>(Qh0 + (size_t)myq * 64 + 32 + g * 8);
    qa[1][0] = *reinterpret_cast<const bf16x8*>(Qh1 + (size_t)myq * 64 + g * 8);
    qa[1][1] = *reinterpret_cast<const bf16x8*>(Qh1 + (size_t)myq * 64 + 32 + g * 8);
  }

  f32x4 lacc[2];
  lacc[0] = (f32x4){0.f, 0.f, 0.f, 0.f};
  lacc[1] = (f32x4){0.f, 0.f, 0.f, 0.f};
  f32x4 o[2][4];
#pragma unroll
  for (int bt = 0; bt < 2; bt++)
#pragma unroll
    for (int f = 0; f < 4; f++) o[bt][f] = (f32x4){0.f, 0.f, 0.f, 0.f};

  // deferred-PV state: P fragments and V fragments of the PREVIOUS chunk
  bf16x8 pfP[2][2];     // [bt][kk]
  bf16x8 vfP[2][2][4];  // [bt][kk][fd]

  f32x4 bA[4], bB[4];
  const float NM = -FIXED_M * LOG2E;

  auto process = [&](int db, f32x4 (&bv)[4], bool do_pv) {
    // this chunk's stage+bias drained; next stage(8)+bias(4) stay in flight
    asm volatile("s_waitcnt vmcnt(12)" ::: "memory");
    __builtin_amdgcn_s_barrier();
    f32x4 st[2][4];
    __builtin_amdgcn_s_setprio(1);
    // QK(t) for both batches (LDS reads + MFMA, bias C-init)
#pragma unroll
    for (int bt = 0; bt < 2; bt++) {
      const char* Kl = (const char*)&KVs[db][bt][0][0][0];
#pragma unroll
      for (int f = 0; f < 4; f++) {
        const char* rb = Kl + (f * 16 + c) * 128;
        bf16x8 k0 = *reinterpret_cast<const bf16x8*>(rb + ((g * 16) ^ swz));
        bf16x8 k1 = *reinterpret_cast<const bf16x8*>(rb + ((64 + g * 16) ^ swz));
        st[bt][f] = mfma16(k1, qa[bt][1], mfma16(k0, qa[bt][0], bv[f]));
      }
    }
    // deferred PV(t-1): pure register MFMAs, overlap QK's LDS latency
    if (do_pv) {
#pragma unroll
      for (int bt = 0; bt < 2; bt++)
#pragma unroll
        for (int kk = 0; kk < 2; kk++)
#pragma unroll
          for (int fd = 0; fd < 4; fd++)
            o[bt][fd] = mfma16(vfP[bt][kk][fd], pfP[bt][kk], o[bt][fd]);
    }
    __builtin_amdgcn_s_setprio(0);
    // fixed-max softmax + pack P fragments for NEXT iteration's PV
#pragma unroll
    for (int bt = 0; bt < 2; bt++) {
#pragma unroll
      for (int f = 0; f < 4; f++) {
#pragma unroll
        for (int r = 0; r < 4; r++)
          st[bt][f][r] = __builtin_exp2f(__builtin_fmaf(st[bt][f][r], LOG2E, NM));
        lacc[bt] += st[bt][f];
      }
#pragma unroll
      for (int kk = 0; kk < 2; kk++)
        pfP[bt][kk] = (bf16x8){(__bf16)st[bt][2 * kk][0],     (__bf16)st[bt][2 * kk][1],
                               (__bf16)st[bt][2 * kk][2],     (__bf16)st[bt][2 * kk][3],
                               (__bf16)st[bt][2 * kk + 1][0], (__bf16)st[bt][2 * kk + 1][1],
                               (__bf16)st[bt][2 * kk + 1][2], (__bf16)st[bt][2 * kk + 1][3]};
    }
    // read V fragments of THIS chunk (custom k-map, 2x b64 per frag) before barrier
#pragma unroll
    for (int bt = 0; bt < 2; bt++) {
      const char* Vl = (const char*)&KVs[db][bt][1][0][0];
#pragma unroll
      for (int kk = 0; kk < 2; kk++)
#pragma unroll
        for (int fd = 0; fd < 4; fd++) {
          const char* rb = Vl + (fd * 16 + c) * 128;
          u32x2 lo = *reinterpret_cast<const u32x2*>(rb + ((kk * 64 + g * 8) ^ swz));
          u32x2 hi = *reinterpret_cast<const u32x2*>(rb + ((kk * 64 + 32 + g * 8) ^ swz));
          u32x4 w = {lo[0], lo[1], hi[0], hi[1]};
          vfP[bt][kk][fd] = __builtin_bit_cast(bf16x8, w);
        }
    }
    __builtin_amdgcn_s_barrier();  // all waves done reading KVs[db]
  };

  // prologue
  stage(0, 0);
  asm volatile("" ::: "memory");
  stage(1, 1);
  asm volatile("" ::: "memory");
  LOADB(bA, 0);
  asm volatile("" ::: "memory");
  LOADB(bB, 1);
  asm volatile("" ::: "memory");

  // peeled first pair (chunk 0 has no PV-prev)
  process(0, bA, false);
  stage(0, 2);
  asm volatile("" ::: "memory");
  LOADB(bA, 2);
  asm volatile("" ::: "memory");
  process(1, bB, true);
  stage(1, 3);
  asm volatile("" ::: "memory");
  LOADB(bB, 3);
  asm volatile("" ::: "memory");

  for (int t = 2; t < 64; t += 2) {
    process(0, bA, true);
    stage(0, (t + 2) & 63);
    asm volatile("" ::: "memory");
    LOADB(bA, ((t + 2) & 63));
    asm volatile("" ::: "memory");
    process(1, bB, true);
    stage(1, (t + 3) & 63);
    asm volatile("" ::: "memory");
    LOADB(bB, ((t + 3) & 63));
    asm volatile("" ::: "memory");
  }

  // tail flush: PV of chunk 63
#pragma unroll
  for (int bt = 0; bt < 2; bt++)
#pragma unroll
    for (int kk = 0; kk < 2; kk++)
#pragma unroll
      for (int fd = 0; fd < 4; fd++)
        o[bt][fd] = mfma16(vfP[bt][kk][fd], pfP[bt][kk], o[bt][fd]);

  // epilogue per batch: reduce l over g-groups, normalize, packed store
#pragma unroll
  for (int bt = 0; bt < 2; bt++) {
    float l = lacc[bt][0] + lacc[bt][1] + lacc[bt][2] + lacc[bt][3];
    l += __shfl_xor(l, 16);
    l += __shfl_xor(l, 32);
    float inv = 1.f / l;
    __bf16* Orow = Out + ((size_t)bt * 4096 + myq) * 512 + h * 64;
#pragma unroll
    for (int fd = 0; fd < 4; fd++) {
      bf16x4 ov = {(__bf16)(o[bt][fd][0] * inv), (__bf16)(o[bt][fd][1] * inv),
                   (__bf16)(o[bt][fd][2] * inv), (__bf16)(o[bt][fd][3] * inv)};
      *reinterpret_cast<bf16x4*>(Orow + fd * 16 + g * 4) = ov;
    }
  }
#undef LOADB
}

// ---------------- launch ----------------
extern "C" void kernel_launch(void* const* d_in, const int* in_sizes, int n_in,
                              void* d_out, int out_size, void* d_ws, size_t ws_size,
                              hipStream_t stream) {
  const float* xq = (const float*)d_in[0];
  const float* xm = (const float*)d_in[1];
  const float* bias = (const float*)d_in[2];
  const float* Wq = (const float*)d_in[3];
  const float* Wk = (const float*)d_in[4];
  const float* Wv = (const float*)d_in[5];
  const float* Wo = (const float*)d_in[6];

  const size_t MB = 1024 * 1024;
  char* ws = (char*)d_ws;
  __bf16* xq_b = (__bf16*)(ws + 0);
  __bf16* xm_b = (__bf16*)(ws + 8 * MB);
  __bf16* wqt = (__bf16*)(ws + 16 * MB);
  __bf16* wkt = (__bf16*)(ws + 16 * MB + 524288);
  __bf16* wvt = (__bf16*)(ws + 17 * MB);
  __bf16* wot = (__bf16*)(ws + 17 * MB + 524288);
  __bf16* Qb = (__bf16*)(ws + 18 * MB);
  __bf16* Kb = (__bf16*)(ws + 26 * MB);
  __bf16* AOb = (__bf16*)(ws + 34 * MB);
  __bf16* Vtb = (__bf16*)(ws + 42 * MB);
  if (ws_size < 50 * MB) return;

  const int n4 = 8192 * 512 / 4;
  k_cvt<<<2048, 256, 0, stream>>>(xq, xq_b, n4);
  k_cvt<<<2048, 256, 0, stream>>>(xm, xm_b, n4);
  k_wt<<<dim3(8, 8), 256, 0, stream>>>(Wq, wqt);
  k_wt<<<dim3(8, 8), 256, 0, stream>>>(Wk, wkt);
  k_wt<<<dim3(8, 8), 256, 0, stream>>>(Wv, wvt);
  k_wt<<<dim3(8, 8), 256, 0, stream>>>(Wo, wot);

  k_gemm<0><<<dim3(64, 8), 256, 0, stream>>>(xq_b, wqt, Qb, 0.125f);
  k_gemm<0><<<dim3(64, 8), 256, 0, stream>>>(xm_b, wkt, Kb, 1.0f);
  k_gemm<2><<<dim3(64, 8), 256, 0, stream>>>(xm_b, wvt, Vtb, 1.0f);

  k_attn<<<512, 256, 0, stream>>>(Qb, Kb, Vtb, bias, AOb);

  k_gemm<1><<<dim3(64, 8), 256, 0, stream>>>(AOb, wot, d_out, 1.0f);
}

// Round 15
// 217.458 us; speedup vs baseline: 1.2708x; 1.2708x over previous
//
#include <hip/hip_runtime.h>
#include <hip/hip_bf16.h>

typedef __attribute__((ext_vector_type(8))) __bf16 bf16x8;
typedef __attribute__((ext_vector_type(4))) __bf16 bf16x4;
typedef __attribute__((ext_vector_type(4))) float f32x4;
typedef __attribute__((ext_vector_type(2))) unsigned u32x2;
typedef __attribute__((ext_vector_type(4))) unsigned u32x4;

#define LOG2E 1.4426950408889634f
#define FIXED_M 16.0f

static __device__ __forceinline__ f32x4 mfma16(bf16x8 a, bf16x8 b, f32x4 c) {
  return __builtin_amdgcn_mfma_f32_16x16x32_bf16(a, b, c, 0, 0, 0);
}

static __device__ __forceinline__ void gload_lds16(const void* g, void* l) {
  __builtin_amdgcn_global_load_lds(
      (const __attribute__((address_space(1))) unsigned int*)g,
      (__attribute__((address_space(3))) unsigned int*)l, 16, 0, 0);
}

// ---------------- f32 -> bf16 convert, both inputs in one launch ----------------
__global__ __launch_bounds__(256) void k_cvt2(const float* __restrict__ a,
                                              const float* __restrict__ b,
                                              __bf16* __restrict__ oa,
                                              __bf16* __restrict__ ob, int n4each) {
  int total = 2 * n4each;
  for (int i = blockIdx.x * blockDim.x + threadIdx.x; i < total;
       i += gridDim.x * blockDim.x) {
    const float* src = (i < n4each) ? a : b;
    __bf16* dst = (i < n4each) ? oa : ob;
    int j = (i < n4each) ? i : i - n4each;
    float4 v = reinterpret_cast<const float4*>(src)[j];
    bf16x4 o = {(__bf16)v.x, (__bf16)v.y, (__bf16)v.z, (__bf16)v.w};
    reinterpret_cast<bf16x4*>(dst)[j] = o;
  }
}

// ---------------- weight convert + transpose, all 4 weights in one launch ----------------
__global__ __launch_bounds__(256) void k_wt4(const float* __restrict__ W0,
                                             const float* __restrict__ W1,
                                             const float* __restrict__ W2,
                                             const float* __restrict__ W3,
                                             __bf16* __restrict__ T0,
                                             __bf16* __restrict__ T1,
                                             __bf16* __restrict__ T2,
                                             __bf16* __restrict__ T3) {
  __shared__ float tile[64][65];
  const int z = blockIdx.z;
  const float* W = (z == 0) ? W0 : (z == 1) ? W1 : (z == 2) ? W2 : W3;
  __bf16* Wt = (z == 0) ? T0 : (z == 1) ? T1 : (z == 2) ? T2 : T3;
  int bx = blockIdx.x;
  int by = blockIdx.y;
  int tid = threadIdx.x;
#pragma unroll
  for (int p = 0; p < 16; p++) {
    int idx = p * 256 + tid;
    int r = idx >> 6, c = idx & 63;
    tile[r][c] = W[(size_t)(by * 64 + r) * 512 + bx * 64 + c];
  }
  __syncthreads();
#pragma unroll
  for (int p = 0; p < 16; p++) {
    int idx = p * 256 + tid;
    int rn = idx >> 6, ck = idx & 63;
    Wt[(size_t)(bx * 64 + rn) * 512 + by * 64 + ck] = (__bf16)tile[ck][rn];
  }
}

// ---------------- GEMM: C[M,512] = A[M,512](bf16) @ W (via Wt[n][k] bf16) ----------------
// global_load_lds staging (m97 pattern): linear XOR-swizzled LDS, syncthreads drains vmcnt.
// OUT_MODE 0: bf16 head-layout [B,H,S,64]; 1: f32 [M,512]; 2: bf16 Vt [B,H,64,S].
template <int OUT_MODE>
__global__ __launch_bounds__(256) void k_gemm(const __bf16* __restrict__ A,
                                              const __bf16* __restrict__ Bt,
                                              void* __restrict__ Cout,
                                              float scale) {
  constexpr bool SWAP = (OUT_MODE != 2);
  __shared__ __bf16 As[128][64];  // linear, XOR-swizzled (^(row&7)<<4 on byte cols)
  __shared__ __bf16 Bs[64][64];
  const int tid = threadIdx.x;
  const int wid = tid >> 6, lane = tid & 63;
  const int g = lane >> 4, c = lane & 15;
  const int swz = (c & 7) << 4;
  const int m0 = blockIdx.x * 128, n0 = blockIdx.y * 64;
  const int wr = wid >> 1, wc = wid & 1;
  const char* Ab = (const char*)A;
  const char* Bb = (const char*)Bt;

  f32x4 acc[4][2];
#pragma unroll
  for (int i = 0; i < 4; i++)
#pragma unroll
    for (int j = 0; j < 2; j++) acc[i][j] = (f32x4){0.f, 0.f, 0.f, 0.f};

  for (int k0 = 0; k0 < 512; k0 += 64) {
    // stage A (16KB, 4 passes) + B (8KB, 2 passes), pre-swizzled global source
#pragma unroll
    for (int p = 0; p < 4; p++) {
      int Lp = p * 4096 + tid * 16;
      int L = Lp ^ (((Lp >> 7) & 7) << 4);
      gload_lds16(Ab + (size_t)(m0 + (L >> 7)) * 1024 + k0 * 2 + (L & 127),
                  (char*)As + Lp);
    }
#pragma unroll
    for (int p = 0; p < 2; p++) {
      int Lp = p * 4096 + tid * 16;
      int L = Lp ^ (((Lp >> 7) & 7) << 4);
      gload_lds16(Bb + (size_t)(n0 + (L >> 7)) * 1024 + k0 * 2 + (L & 127),
                  (char*)Bs + Lp);
    }
    __syncthreads();  // drains vmcnt (gload_lds) + barrier
#pragma unroll
    for (int kk = 0; kk < 2; kk++) {
      bf16x8 bfrag[2];
#pragma unroll
      for (int nf = 0; nf < 2; nf++) {
        int row = wc * 32 + nf * 16 + c;
        bfrag[nf] = *reinterpret_cast<const bf16x8*>(
            (const char*)Bs + row * 128 + ((kk * 64 + g * 16) ^ swz));
      }
#pragma unroll
      for (int mf = 0; mf < 4; mf++) {
        int row = wr * 64 + mf * 16 + c;
        bf16x8 afrag = *reinterpret_cast<const bf16x8*>(
            (const char*)As + row * 128 + ((kk * 64 + g * 16) ^ swz));
#pragma unroll
        for (int nf = 0; nf < 2; nf++)
          acc[mf][nf] = SWAP ? mfma16(bfrag[nf], afrag, acc[mf][nf])
                             : mfma16(afrag, bfrag[nf], acc[mf][nf]);
      }
    }
    __syncthreads();
  }
#pragma unroll
  for (int mf = 0; mf < 4; mf++)
#pragma unroll
    for (int nf = 0; nf < 2; nf++) {
      if (OUT_MODE == 0) {
        int mm = m0 + wr * 64 + mf * 16 + c;
        int nnb = n0 + wc * 32 + nf * 16 + g * 4;
        int b = mm >> 12, s = mm & 4095, h = nnb >> 6, d = nnb & 63;
        bf16x4 ov = {(__bf16)(acc[mf][nf][0] * scale), (__bf16)(acc[mf][nf][1] * scale),
                     (__bf16)(acc[mf][nf][2] * scale), (__bf16)(acc[mf][nf][3] * scale)};
        *reinterpret_cast<bf16x4*>((__bf16*)Cout + ((((size_t)b * 8 + h) * 4096) + s) * 64 + d) = ov;
      } else if (OUT_MODE == 1) {
        int mm = m0 + wr * 64 + mf * 16 + c;
        int nnb = n0 + wc * 32 + nf * 16 + g * 4;
        f32x4 ov = acc[mf][nf] * scale;
        *reinterpret_cast<f32x4*>((float*)Cout + (size_t)mm * 512 + nnb) = ov;
      } else {
        int mmb = m0 + wr * 64 + mf * 16 + g * 4;
        int nn = n0 + wc * 32 + nf * 16 + c;
        int b = mmb >> 12, s = mmb & 4095, h = nn >> 6, d = nn & 63;
        bf16x4 ov = {(__bf16)(acc[mf][nf][0] * scale), (__bf16)(acc[mf][nf][1] * scale),
                     (__bf16)(acc[mf][nf][2] * scale), (__bf16)(acc[mf][nf][3] * scale)};
        *reinterpret_cast<bf16x4*>((__bf16*)Cout + (((size_t)b * 8 + h) * 64 + d) * 4096 + s) = ov;
      }
    }
}

// ---------------- flash attention: r13 verbatim (best verified: 186 us) ----------------
// batch-paired blocks (bias shared), fixed-max softmax, LDS-staged K/V both batches,
// counted-vmcnt pipeline, P in registers.
__global__ __launch_bounds__(256, 2) void k_attn(const __bf16* __restrict__ Q,
                                                 const __bf16* __restrict__ K,
                                                 const __bf16* __restrict__ Vt,
                                                 const float* __restrict__ bias,
                                                 __bf16* __restrict__ Out) {
  __shared__ __bf16 KVs[2][2][2][64][64];  // [dbuf][batch][K/V][row][64], XOR-swz (^(row&7)<<4)

  const int id = blockIdx.x;
  const int qb = ((id >> 6) << 3) | (id & 7);  // 0..63
  const int h = (id >> 3) & 7;
  const int tid = threadIdx.x, wid = tid >> 6, lane = tid & 63;
  const int g = lane >> 4, c = lane & 15;
  const int swz = (c & 7) << 4;
  const char* KbP[2] = {(const char*)(K + (size_t)h * 4096 * 64),
                        (const char*)(K + (size_t)(8 + h) * 4096 * 64)};
  const char* VbP[2] = {(const char*)(Vt + (size_t)h * 64 * 4096),
                        (const char*)(Vt + (size_t)(8 + h) * 64 * 4096)};
  const int q0 = qb * 64 + wid * 16;
  const int myq = q0 + c;

  auto stage = [&](int db, int chunk) {
    const int bt = wid >> 1, reg = wid & 1;
    char* dst0 = (char*)&KVs[db][bt][reg][0][0];
#pragma unroll
    for (int j = 0; j < 8; j++) {
      int Lp = j * 1024 + lane * 16;
      int L = Lp ^ (((Lp >> 7) & 7) << 4);
      const char* src = (reg == 0)
          ? KbP[bt] + (size_t)chunk * 8192 + L
          : VbP[bt] + (size_t)(L >> 7) * 8192 + (size_t)chunk * 128 + (L & 127);
      gload_lds16(src, dst0 + j * 1024);
    }
  };

  const float* brow = bias + (size_t)myq * 4096;

#define LOADB(dst, chunk)                                                      \
  {                                                                            \
    _Pragma("unroll") for (int f = 0; f < 4; f++) dst[f] =                     \
        *reinterpret_cast<const f32x4*>(brow + (chunk) * 64 + f * 16 + g * 4); \
  }

  bf16x8 qa[2][2];
  {
    const __bf16* Qh0 = Q + (size_t)h * 4096 * 64;
    const __bf16* Qh1 = Q + (size_t)(8 + h) * 4096 * 64;
    qa[0][0] = *reinterpret_cast<const bf16x8*>(Qh0 + (size_t)myq * 64 + g * 8);
    qa[0][1] = *reinterpret_cast<const bf16x8*>(Qh0 + (size_t)myq * 64 + 32 + g * 8);
    qa[1][0] = *reinterpret_cast<const bf16x8*>(Qh1 + (size_t)myq * 64 + g * 8);
    qa[1][1] = *reinterpret_cast<const bf16x8*>(Qh1 + (size_t)myq * 64 + 32 + g * 8);
  }

  f32x4 lacc[2];
  lacc[0] = (f32x4){0.f, 0.f, 0.f, 0.f};
  lacc[1] = (f32x4){0.f, 0.f, 0.f, 0.f};
  f32x4 o[2][4];
#pragma unroll
  for (int bt = 0; bt < 2; bt++)
#pragma unroll
    for (int f = 0; f < 4; f++) o[bt][f] = (f32x4){0.f, 0.f, 0.f, 0.f};

  f32x4 bA[4], bB[4];
  const float NM = -FIXED_M * LOG2E;

  auto process = [&](int db, f32x4 (&bv)[4]) {
    // this chunk's stage drained; next stage(8)+bias(4) stay in flight
    asm volatile("s_waitcnt vmcnt(12)" ::: "memory");
    __builtin_amdgcn_s_barrier();
#pragma unroll
    for (int bt = 0; bt < 2; bt++) {
      const char* Kl = (const char*)&KVs[db][bt][0][0][0];
      const char* Vl = (const char*)&KVs[db][bt][1][0][0];
      f32x4 st[4];
      __builtin_amdgcn_s_setprio(1);
#pragma unroll
      for (int f = 0; f < 4; f++) {
        const char* rb = Kl + (f * 16 + c) * 128;
        bf16x8 k0 = *reinterpret_cast<const bf16x8*>(rb + ((g * 16) ^ swz));
        bf16x8 k1 = *reinterpret_cast<const bf16x8*>(rb + ((64 + g * 16) ^ swz));
        st[f] = mfma16(k1, qa[bt][1], mfma16(k0, qa[bt][0], bv[f]));  // shared bias C-init
      }
      __builtin_amdgcn_s_setprio(0);
      // V fragments, custom k-map (r11-verified): 2x b64 per frag
      bf16x8 vf[2][4];
#pragma unroll
      for (int kk = 0; kk < 2; kk++)
#pragma unroll
        for (int fd = 0; fd < 4; fd++) {
          const char* rb = Vl + (fd * 16 + c) * 128;
          u32x2 lo = *reinterpret_cast<const u32x2*>(rb + ((kk * 64 + g * 8) ^ swz));
          u32x2 hi = *reinterpret_cast<const u32x2*>(rb + ((kk * 64 + 32 + g * 8) ^ swz));
          u32x4 w = {lo[0], lo[1], hi[0], hi[1]};
          vf[kk][fd] = __builtin_bit_cast(bf16x8, w);
        }
      // fixed-max softmax; P stays in registers (lane's own quads)
#pragma unroll
      for (int f = 0; f < 4; f++) {
#pragma unroll
        for (int r = 0; r < 4; r++)
          st[f][r] = __builtin_exp2f(__builtin_fmaf(st[f][r], LOG2E, NM));
        lacc[bt] += st[f];
      }
      __builtin_amdgcn_s_setprio(1);
#pragma unroll
      for (int kk = 0; kk < 2; kk++) {
        bf16x8 pf = {(__bf16)st[2 * kk][0],     (__bf16)st[2 * kk][1],
                     (__bf16)st[2 * kk][2],     (__bf16)st[2 * kk][3],
                     (__bf16)st[2 * kk + 1][0], (__bf16)st[2 * kk + 1][1],
                     (__bf16)st[2 * kk + 1][2], (__bf16)st[2 * kk + 1][3]};
#pragma unroll
        for (int fd = 0; fd < 4; fd++)
          o[bt][fd] = mfma16(vf[kk][fd], pf, o[bt][fd]);
      }
      __builtin_amdgcn_s_setprio(0);
    }
    __builtin_amdgcn_s_barrier();  // all waves done reading KVs[db]
  };

  // prologue
  stage(0, 0);
  asm volatile("" ::: "memory");
  stage(1, 1);
  asm volatile("" ::: "memory");
  LOADB(bA, 0);
  asm volatile("" ::: "memory");
  LOADB(bB, 1);
  asm volatile("" ::: "memory");

  for (int t = 0; t < 64; t += 2) {
    process(0, bA);
    stage(0, (t + 2) & 63);
    asm volatile("" ::: "memory");
    LOADB(bA, ((t + 2) & 63));
    asm volatile("" ::: "memory");
    process(1, bB);
    stage(1, (t + 3) & 63);
    asm volatile("" ::: "memory");
    LOADB(bB, ((t + 3) & 63));
    asm volatile("" ::: "memory");
  }

  // epilogue per batch: reduce l over g-groups, normalize, packed store
#pragma unroll
  for (int bt = 0; bt < 2; bt++) {
    float l = lacc[bt][0] + lacc[bt][1] + lacc[bt][2] + lacc[bt][3];
    l += __shfl_xor(l, 16);
    l += __shfl_xor(l, 32);
    float inv = 1.f / l;
    __bf16* Orow = Out + ((size_t)bt * 4096 + myq) * 512 + h * 64;
#pragma unroll
    for (int fd = 0; fd < 4; fd++) {
      bf16x4 ov = {(__bf16)(o[bt][fd][0] * inv), (__bf16)(o[bt][fd][1] * inv),
                   (__bf16)(o[bt][fd][2] * inv), (__bf16)(o[bt][fd][3] * inv)};
      *reinterpret_cast<bf16x4*>(Orow + fd * 16 + g * 4) = ov;
    }
  }
#undef LOADB
}

// ---------------- launch ----------------
extern "C" void kernel_launch(void* const* d_in, const int* in_sizes, int n_in,
                              void* d_out, int out_size, void* d_ws, size_t ws_size,
                              hipStream_t stream) {
  const float* xq = (const float*)d_in[0];
  const float* xm = (const float*)d_in[1];
  const float* bias = (const float*)d_in[2];
  const float* Wq = (const float*)d_in[3];
  const float* Wk = (const float*)d_in[4];
  const float* Wv = (const float*)d_in[5];
  const float* Wo = (const float*)d_in[6];

  const size_t MB = 1024 * 1024;
  char* ws = (char*)d_ws;
  __bf16* xq_b = (__bf16*)(ws + 0);
  __bf16* xm_b = (__bf16*)(ws + 8 * MB);
  __bf16* wqt = (__bf16*)(ws + 16 * MB);
  __bf16* wkt = (__bf16*)(ws + 16 * MB + 524288);
  __bf16* wvt = (__bf16*)(ws + 17 * MB);
  __bf16* wot = (__bf16*)(ws + 17 * MB + 524288);
  __bf16* Qb = (__bf16*)(ws + 18 * MB);
  __bf16* Kb = (__bf16*)(ws + 26 * MB);
  __bf16* AOb = (__bf16*)(ws + 34 * MB);
  __bf16* Vtb = (__bf16*)(ws + 42 * MB);
  if (ws_size < 50 * MB) return;

  const int n4 = 8192 * 512 / 4;
  k_cvt2<<<4096, 256, 0, stream>>>(xq, xm, xq_b, xm_b, n4);
  k_wt4<<<dim3(8, 8, 4), 256, 0, stream>>>(Wq, Wk, Wv, Wo, wqt, wkt, wvt, wot);

  k_gemm<0><<<dim3(64, 8), 256, 0, stream>>>(xq_b, wqt, Qb, 0.125f);
  k_gemm<0><<<dim3(64, 8), 256, 0, stream>>>(xm_b, wkt, Kb, 1.0f);
  k_gemm<2><<<dim3(64, 8), 256, 0, stream>>>(xm_b, wvt, Vtb, 1.0f);

  k_attn<<<512, 256, 0, stream>>>(Qb, Kb, Vtb, bias, AOb);

  k_gemm<1><<<dim3(64, 8), 256, 0, stream>>>(AOb, wot, d_out, 1.0f);
}

// Round 16
// 201.295 us; speedup vs baseline: 1.3729x; 1.0803x over previous
//
#include <hip/hip_runtime.h>
#include <hip/hip_bf16.h>

typedef __attribute__((ext_vector_type(8))) __bf16 bf16x8;
typedef __attribute__((ext_vector_type(4))) __bf16 bf16x4;
typedef __attribute__((ext_vector_type(4))) float f32x4;

#define LOG2E 1.4426950408889634f
#define FIXED_M 16.0f

static __device__ __forceinline__ f32x4 mfma16(bf16x8 a, bf16x8 b, f32x4 c) {
  return __builtin_amdgcn_mfma_f32_16x16x32_bf16(a, b, c, 0, 0, 0);
}

static __device__ __forceinline__ void gload_lds16(const void* g, void* l) {
  __builtin_amdgcn_global_load_lds(
      (const __attribute__((address_space(1))) unsigned int*)g,
      (__attribute__((address_space(3))) unsigned int*)l, 16, 0, 0);
}

// ---------------- f32 -> bf16 convert, both inputs in one launch ----------------
__global__ __launch_bounds__(256) void k_cvt2(const float* __restrict__ a,
                                              const float* __restrict__ b,
                                              __bf16* __restrict__ oa,
                                              __bf16* __restrict__ ob, int n4each) {
  int total = 2 * n4each;
  for (int i = blockIdx.x * blockDim.x + threadIdx.x; i < total;
       i += gridDim.x * blockDim.x) {
    const float* src = (i < n4each) ? a : b;
    __bf16* dst = (i < n4each) ? oa : ob;
    int j = (i < n4each) ? i : i - n4each;
    float4 v = reinterpret_cast<const float4*>(src)[j];
    bf16x4 o = {(__bf16)v.x, (__bf16)v.y, (__bf16)v.z, (__bf16)v.w};
    reinterpret_cast<bf16x4*>(dst)[j] = o;
  }
}

// ---------------- weight convert + transpose, all 4 weights in one launch ----------------
__global__ __launch_bounds__(256) void k_wt4(const float* __restrict__ W0,
                                             const float* __restrict__ W1,
                                             const float* __restrict__ W2,
                                             const float* __restrict__ W3,
                                             __bf16* __restrict__ T0,
                                             __bf16* __restrict__ T1,
                                             __bf16* __restrict__ T2,
                                             __bf16* __restrict__ T3) {
  __shared__ float tile[64][65];
  const int z = blockIdx.z;
  const float* W = (z == 0) ? W0 : (z == 1) ? W1 : (z == 2) ? W2 : W3;
  __bf16* Wt = (z == 0) ? T0 : (z == 1) ? T1 : (z == 2) ? T2 : T3;
  int bx = blockIdx.x;
  int by = blockIdx.y;
  int tid = threadIdx.x;
#pragma unroll
  for (int p = 0; p < 16; p++) {
    int idx = p * 256 + tid;
    int r = idx >> 6, c = idx & 63;
    tile[r][c] = W[(size_t)(by * 64 + r) * 512 + bx * 64 + c];
  }
  __syncthreads();
#pragma unroll
  for (int p = 0; p < 16; p++) {
    int idx = p * 256 + tid;
    int rn = idx >> 6, ck = idx & 63;
    Wt[(size_t)(bx * 64 + rn) * 512 + by * 64 + ck] = (__bf16)tile[ck][rn];
  }
}

// ---------------- GEMM: C[M,512] = A[M,512](bf16) @ W (via Wt[n][k] bf16) ----------------
// global_load_lds staging (m97 pattern): linear XOR-swizzled LDS, syncthreads drains vmcnt.
// OUT_MODE 0: bf16 head-layout [B,H,S,64]; 1: f32 [M,512];
// OUT_MODE 2: bf16 Vt [B,H,64,S] with PV k-map permutation baked into each 64-chunk:
//             pos(s%64) = g*16 + (f>>1)*8 + (f&1)*4 + r  for s%64 = 16f+4g+r.
template <int OUT_MODE>
__global__ __launch_bounds__(256) void k_gemm(const __bf16* __restrict__ A,
                                              const __bf16* __restrict__ Bt,
                                              void* __restrict__ Cout,
                                              float scale) {
  constexpr bool SWAP = (OUT_MODE != 2);
  __shared__ __bf16 As[128][64];  // linear, XOR-swizzled (^(row&7)<<4 on byte cols)
  __shared__ __bf16 Bs[64][64];
  const int tid = threadIdx.x;
  const int wid = tid >> 6, lane = tid & 63;
  const int g = lane >> 4, c = lane & 15;
  const int swz = (c & 7) << 4;
  const int m0 = blockIdx.x * 128, n0 = blockIdx.y * 64;
  const int wr = wid >> 1, wc = wid & 1;
  const char* Ab = (const char*)A;
  const char* Bb = (const char*)Bt;

  f32x4 acc[4][2];
#pragma unroll
  for (int i = 0; i < 4; i++)
#pragma unroll
    for (int j = 0; j < 2; j++) acc[i][j] = (f32x4){0.f, 0.f, 0.f, 0.f};

  for (int k0 = 0; k0 < 512; k0 += 64) {
#pragma unroll
    for (int p = 0; p < 4; p++) {
      int Lp = p * 4096 + tid * 16;
      int L = Lp ^ (((Lp >> 7) & 7) << 4);
      gload_lds16(Ab + (size_t)(m0 + (L >> 7)) * 1024 + k0 * 2 + (L & 127),
                  (char*)As + Lp);
    }
#pragma unroll
    for (int p = 0; p < 2; p++) {
      int Lp = p * 4096 + tid * 16;
      int L = Lp ^ (((Lp >> 7) & 7) << 4);
      gload_lds16(Bb + (size_t)(n0 + (L >> 7)) * 1024 + k0 * 2 + (L & 127),
                  (char*)Bs + Lp);
    }
    __syncthreads();  // drains vmcnt (gload_lds) + barrier
#pragma unroll
    for (int kk = 0; kk < 2; kk++) {
      bf16x8 bfrag[2];
#pragma unroll
      for (int nf = 0; nf < 2; nf++) {
        int row = wc * 32 + nf * 16 + c;
        bfrag[nf] = *reinterpret_cast<const bf16x8*>(
            (const char*)Bs + row * 128 + ((kk * 64 + g * 16) ^ swz));
      }
#pragma unroll
      for (int mf = 0; mf < 4; mf++) {
        int row = wr * 64 + mf * 16 + c;
        bf16x8 afrag = *reinterpret_cast<const bf16x8*>(
            (const char*)As + row * 128 + ((kk * 64 + g * 16) ^ swz));
#pragma unroll
        for (int nf = 0; nf < 2; nf++)
          acc[mf][nf] = SWAP ? mfma16(bfrag[nf], afrag, acc[mf][nf])
                             : mfma16(afrag, bfrag[nf], acc[mf][nf]);
      }
    }
    __syncthreads();
  }
#pragma unroll
  for (int mf = 0; mf < 4; mf++)
#pragma unroll
    for (int nf = 0; nf < 2; nf++) {
      if (OUT_MODE == 0) {
        int mm = m0 + wr * 64 + mf * 16 + c;
        int nnb = n0 + wc * 32 + nf * 16 + g * 4;
        int b = mm >> 12, s = mm & 4095, h = nnb >> 6, d = nnb & 63;
        bf16x4 ov = {(__bf16)(acc[mf][nf][0] * scale), (__bf16)(acc[mf][nf][1] * scale),
                     (__bf16)(acc[mf][nf][2] * scale), (__bf16)(acc[mf][nf][3] * scale)};
        *reinterpret_cast<bf16x4*>((__bf16*)Cout + ((((size_t)b * 8 + h) * 4096) + s) * 64 + d) = ov;
      } else if (OUT_MODE == 1) {
        int mm = m0 + wr * 64 + mf * 16 + c;
        int nnb = n0 + wc * 32 + nf * 16 + g * 4;
        f32x4 ov = acc[mf][nf] * scale;
        *reinterpret_cast<f32x4*>((float*)Cout + (size_t)mm * 512 + nnb) = ov;
      } else {
        // Vt permuted: s = mmb quad (f=mf, g=g, r=0..3); chunk = s>>6;
        // pos = g*16 + (mf>>1)*8 + (mf&1)*4 (+r contiguous)
        int mmb = m0 + wr * 64 + mf * 16 + g * 4;
        int nn = n0 + wc * 32 + nf * 16 + c;
        int b = mmb >> 12, s = mmb & 4095, h = nn >> 6, d = nn & 63;
        int chunk = s >> 6;
        int pos = g * 16 + (mf >> 1) * 8 + (mf & 1) * 4;
        bf16x4 ov = {(__bf16)(acc[mf][nf][0] * scale), (__bf16)(acc[mf][nf][1] * scale),
                     (__bf16)(acc[mf][nf][2] * scale), (__bf16)(acc[mf][nf][3] * scale)};
        *reinterpret_cast<bf16x4*>((__bf16*)Cout +
                                   (((size_t)b * 8 + h) * 64 + d) * 4096 + chunk * 64 + pos) = ov;
      }
    }
}

// ---------------- flash attention: r13 structure; V fragments now single b128 reads
// (k-map permutation baked into Vt layout) ----------------
__global__ __launch_bounds__(256, 2) void k_attn(const __bf16* __restrict__ Q,
                                                 const __bf16* __restrict__ K,
                                                 const __bf16* __restrict__ Vt,
                                                 const float* __restrict__ bias,
                                                 __bf16* __restrict__ Out) {
  __shared__ __bf16 KVs[2][2][2][64][64];  // [dbuf][batch][K/V][row][64], XOR-swz (^(row&7)<<4)

  const int id = blockIdx.x;
  const int qb = ((id >> 6) << 3) | (id & 7);  // 0..63
  const int h = (id >> 3) & 7;
  const int tid = threadIdx.x, wid = tid >> 6, lane = tid & 63;
  const int g = lane >> 4, c = lane & 15;
  const int swz = (c & 7) << 4;
  const char* KbP[2] = {(const char*)(K + (size_t)h * 4096 * 64),
                        (const char*)(K + (size_t)(8 + h) * 4096 * 64)};
  const char* VbP[2] = {(const char*)(Vt + (size_t)h * 64 * 4096),
                        (const char*)(Vt + (size_t)(8 + h) * 64 * 4096)};
  const int q0 = qb * 64 + wid * 16;
  const int myq = q0 + c;

  auto stage = [&](int db, int chunk) {
    const int bt = wid >> 1, reg = wid & 1;
    char* dst0 = (char*)&KVs[db][bt][reg][0][0];
#pragma unroll
    for (int j = 0; j < 8; j++) {
      int Lp = j * 1024 + lane * 16;
      int L = Lp ^ (((Lp >> 7) & 7) << 4);
      const char* src = (reg == 0)
          ? KbP[bt] + (size_t)chunk * 8192 + L
          : VbP[bt] + (size_t)(L >> 7) * 8192 + (size_t)chunk * 128 + (L & 127);
      gload_lds16(src, dst0 + j * 1024);
    }
  };

  const float* brow = bias + (size_t)myq * 4096;

#define LOADB(dst, chunk)                                                      \
  {                                                                            \
    _Pragma("unroll") for (int f = 0; f < 4; f++) dst[f] =                     \
        *reinterpret_cast<const f32x4*>(brow + (chunk) * 64 + f * 16 + g * 4); \
  }

  bf16x8 qa[2][2];
  {
    const __bf16* Qh0 = Q + (size_t)h * 4096 * 64;
    const __bf16* Qh1 = Q + (size_t)(8 + h) * 4096 * 64;
    qa[0][0] = *reinterpret_cast<const bf16x8*>(Qh0 + (size_t)myq * 64 + g * 8);
    qa[0][1] = *reinterpret_cast<const bf16x8*>(Qh0 + (size_t)myq * 64 + 32 + g * 8);
    qa[1][0] = *reinterpret_cast<const bf16x8*>(Qh1 + (size_t)myq * 64 + g * 8);
    qa[1][1] = *reinterpret_cast<const bf16x8*>(Qh1 + (size_t)myq * 64 + 32 + g * 8);
  }

  f32x4 lacc[2];
  lacc[0] = (f32x4){0.f, 0.f, 0.f, 0.f};
  lacc[1] = (f32x4){0.f, 0.f, 0.f, 0.f};
  f32x4 o[2][4];
#pragma unroll
  for (int bt = 0; bt < 2; bt++)
#pragma unroll
    for (int f = 0; f < 4; f++) o[bt][f] = (f32x4){0.f, 0.f, 0.f, 0.f};

  f32x4 bA[4], bB[4];
  const float NM = -FIXED_M * LOG2E;

  auto process = [&](int db, f32x4 (&bv)[4]) {
    // this chunk's stage drained; next stage(8)+bias(4) stay in flight
    asm volatile("s_waitcnt vmcnt(12)" ::: "memory");
    __builtin_amdgcn_s_barrier();
#pragma unroll
    for (int bt = 0; bt < 2; bt++) {
      const char* Kl = (const char*)&KVs[db][bt][0][0][0];
      const char* Vl = (const char*)&KVs[db][bt][1][0][0];
      f32x4 st[4];
      __builtin_amdgcn_s_setprio(1);
#pragma unroll
      for (int f = 0; f < 4; f++) {
        const char* rb = Kl + (f * 16 + c) * 128;
        bf16x8 k0 = *reinterpret_cast<const bf16x8*>(rb + ((g * 16) ^ swz));
        bf16x8 k1 = *reinterpret_cast<const bf16x8*>(rb + ((64 + g * 16) ^ swz));
        st[f] = mfma16(k1, qa[bt][1], mfma16(k0, qa[bt][0], bv[f]));  // shared bias C-init
      }
      __builtin_amdgcn_s_setprio(0);
      // V fragments: permuted layout -> single b128 per (kk,fd), K-read bank pattern
      bf16x8 vf[2][4];
#pragma unroll
      for (int kk = 0; kk < 2; kk++)
#pragma unroll
        for (int fd = 0; fd < 4; fd++) {
          const char* rb = Vl + (fd * 16 + c) * 128;
          vf[kk][fd] = *reinterpret_cast<const bf16x8*>(rb + ((g * 32 + kk * 16) ^ swz));
        }
      // fixed-max softmax; P stays in registers (lane's own quads)
#pragma unroll
      for (int f = 0; f < 4; f++) {
#pragma unroll
        for (int r = 0; r < 4; r++)
          st[f][r] = __builtin_exp2f(__builtin_fmaf(st[f][r], LOG2E, NM));
        lacc[bt] += st[f];
      }
      __builtin_amdgcn_s_setprio(1);
#pragma unroll
      for (int kk = 0; kk < 2; kk++) {
        bf16x8 pf = {(__bf16)st[2 * kk][0],     (__bf16)st[2 * kk][1],
                     (__bf16)st[2 * kk][2],     (__bf16)st[2 * kk][3],
                     (__bf16)st[2 * kk + 1][0], (__bf16)st[2 * kk + 1][1],
                     (__bf16)st[2 * kk + 1][2], (__bf16)st[2 * kk + 1][3]};
#pragma unroll
        for (int fd = 0; fd < 4; fd++)
          o[bt][fd] = mfma16(vf[kk][fd], pf, o[bt][fd]);
      }
      __builtin_amdgcn_s_setprio(0);
    }
    __builtin_amdgcn_s_barrier();  // all waves done reading KVs[db]
  };

  // prologue
  stage(0, 0);
  asm volatile("" ::: "memory");
  stage(1, 1);
  asm volatile("" ::: "memory");
  LOADB(bA, 0);
  asm volatile("" ::: "memory");
  LOADB(bB, 1);
  asm volatile("" ::: "memory");

  for (int t = 0; t < 64; t += 2) {
    process(0, bA);
    stage(0, (t + 2) & 63);
    asm volatile("" ::: "memory");
    LOADB(bA, ((t + 2) & 63));
    asm volatile("" ::: "memory");
    process(1, bB);
    stage(1, (t + 3) & 63);
    asm volatile("" ::: "memory");
    LOADB(bB, ((t + 3) & 63));
    asm volatile("" ::: "memory");
  }

  // epilogue per batch: reduce l over g-groups, normalize, packed store
#pragma unroll
  for (int bt = 0; bt < 2; bt++) {
    float l = lacc[bt][0] + lacc[bt][1] + lacc[bt][2] + lacc[bt][3];
    l += __shfl_xor(l, 16);
    l += __shfl_xor(l, 32);
    float inv = 1.f / l;
    __bf16* Orow = Out + ((size_t)bt * 4096 + myq) * 512 + h * 64;
#pragma unroll
    for (int fd = 0; fd < 4; fd++) {
      bf16x4 ov = {(__bf16)(o[bt][fd][0] * inv), (__bf16)(o[bt][fd][1] * inv),
                   (__bf16)(o[bt][fd][2] * inv), (__bf16)(o[bt][fd][3] * inv)};
      *reinterpret_cast<bf16x4*>(Orow + fd * 16 + g * 4) = ov;
    }
  }
#undef LOADB
}

// ---------------- launch ----------------
extern "C" void kernel_launch(void* const* d_in, const int* in_sizes, int n_in,
                              void* d_out, int out_size, void* d_ws, size_t ws_size,
                              hipStream_t stream) {
  const float* xq = (const float*)d_in[0];
  const float* xm = (const float*)d_in[1];
  const float* bias = (const float*)d_in[2];
  const float* Wq = (const float*)d_in[3];
  const float* Wk = (const float*)d_in[4];
  const float* Wv = (const float*)d_in[5];
  const float* Wo = (const float*)d_in[6];

  const size_t MB = 1024 * 1024;
  char* ws = (char*)d_ws;
  __bf16* xq_b = (__bf16*)(ws + 0);
  __bf16* xm_b = (__bf16*)(ws + 8 * MB);
  __bf16* wqt = (__bf16*)(ws + 16 * MB);
  __bf16* wkt = (__bf16*)(ws + 16 * MB + 524288);
  __bf16* wvt = (__bf16*)(ws + 17 * MB);
  __bf16* wot = (__bf16*)(ws + 17 * MB + 524288);
  __bf16* Qb = (__bf16*)(ws + 18 * MB);
  __bf16* Kb = (__bf16*)(ws + 26 * MB);
  __bf16* AOb = (__bf16*)(ws + 34 * MB);
  __bf16* Vtb = (__bf16*)(ws + 42 * MB);
  if (ws_size < 50 * MB) return;

  const int n4 = 8192 * 512 / 4;
  k_cvt2<<<4096, 256, 0, stream>>>(xq, xm, xq_b, xm_b, n4);
  k_wt4<<<dim3(8, 8, 4), 256, 0, stream>>>(Wq, Wk, Wv, Wo, wqt, wkt, wvt, wot);

  k_gemm<0><<<dim3(64, 8), 256, 0, stream>>>(xq_b, wqt, Qb, 0.125f);
  k_gemm<0><<<dim3(64, 8), 256, 0, stream>>>(xm_b, wkt, Kb, 1.0f);
  k_gemm<2><<<dim3(64, 8), 256, 0, stream>>>(xm_b, wvt, Vtb, 1.0f);

  k_attn<<<512, 256, 0, stream>>>(Qb, Kb, Vtb, bias, AOb);

  k_gemm<1><<<dim3(64, 8), 256, 0, stream>>>(AOb, wot, d_out, 1.0f);
}